// Round 3
// baseline (4280.313 us; speedup 1.0000x reference)
//
#include <hip/hip_runtime.h>
#include <hip/hip_fp16.h>

typedef _Float16 half2_t __attribute__((ext_vector_type(2)));
typedef _Float16 half4_t __attribute__((ext_vector_type(4)));
typedef _Float16 half8_t __attribute__((ext_vector_type(8)));
typedef float floatx4 __attribute__((ext_vector_type(4)));

#define B_   32
#define S_   512
#define D_   768
#define H_   384
#define H3_  1152      // 3*H
#define M_   (B_*S_)   // 16384
#define N2_  (2*H3_)   // 2304
#define TWOH_ 768

// ---------------- generic fp32 -> fp16 convert (vec4) ----------------
__global__ void cvt_f32_f16_kernel(const float* __restrict__ src,
                                   _Float16* __restrict__ dst, int n4) {
  int i = blockIdx.x * blockDim.x + threadIdx.x;
  if (i >= n4) return;
  float4 v = ((const float4*)src)[i];
  half4_t h = {(_Float16)v.x, (_Float16)v.y, (_Float16)v.z, (_Float16)v.w};
  ((half4_t*)dst)[i] = h;
}

// ---------------- input-projection GEMM (fp16 MFMA) ----------------
__global__ __launch_bounds__(256) void gemm_xw_kernel(
    const _Float16* __restrict__ A, const _Float16* __restrict__ Bm,
    const float* __restrict__ bias_f, const float* __restrict__ bias_b,
    _Float16* __restrict__ xw) {
  __shared__ _Float16 As[64][40];
  __shared__ _Float16 Bs[64][40];
  const int m0 = blockIdx.x * 64, n0 = blockIdx.y * 64;
  const int tid = threadIdx.x, lane = tid & 63, w = tid >> 6;
  const int wm = w >> 1, wn = w & 1;
  const int q = lane >> 4, c = lane & 15;
  floatx4 acc[2][2] = {};

  const int t = tid & 127;
  const int srow = t >> 1, skh = (t & 1) * 16;
  const _Float16* gsrc =
      (tid < 128 ? A + (size_t)(m0 + srow) * D_ : Bm + (size_t)(n0 + srow) * D_) + skh;
  _Float16* ldst = (tid < 128) ? &As[srow][skh] : &Bs[srow][skh];

  for (int k0 = 0; k0 < D_; k0 += 32) {
    half8_t v0 = *(const half8_t*)(gsrc + k0);
    half8_t v1 = *(const half8_t*)(gsrc + k0 + 8);
    __syncthreads();
    *(half8_t*)ldst = v0;
    *(half8_t*)(ldst + 8) = v1;
    __syncthreads();
    half8_t a0 = *(const half8_t*)&As[wm * 32 + c][q * 8];
    half8_t a1 = *(const half8_t*)&As[wm * 32 + 16 + c][q * 8];
    half8_t b0 = *(const half8_t*)&Bs[wn * 32 + c][q * 8];
    half8_t b1 = *(const half8_t*)&Bs[wn * 32 + 16 + c][q * 8];
    acc[0][0] = __builtin_amdgcn_mfma_f32_16x16x32_f16(a0, b0, acc[0][0], 0, 0, 0);
    acc[0][1] = __builtin_amdgcn_mfma_f32_16x16x32_f16(a0, b1, acc[0][1], 0, 0, 0);
    acc[1][0] = __builtin_amdgcn_mfma_f32_16x16x32_f16(a1, b0, acc[1][0], 0, 0, 0);
    acc[1][1] = __builtin_amdgcn_mfma_f32_16x16x32_f16(a1, b1, acc[1][1], 0, 0, 0);
  }
  for (int mi = 0; mi < 2; ++mi)
    for (int ni = 0; ni < 2; ++ni)
      for (int r = 0; r < 4; ++r) {
        int m = m0 + wm * 32 + mi * 16 + q * 4 + r;
        int n = n0 + wn * 32 + ni * 16 + c;
        int dir = n >= H3_;
        int nn = n - dir * H3_;
        float bv = dir ? bias_b[nn] : bias_f[nn];
        float vv = acc[mi][ni][r] + bv;
        int s = m & (S_ - 1), bb = m >> 9;
        xw[(((size_t)dir * S_ + s) * B_ + bb) * H3_ + nn] = (_Float16)vv;
      }
}

// ---------------- GRU recurrence: weights-in-VGPR MFMA, MALL-coherent h exchange ----
// 48 WGs = 2 dirs x 24 slices of 16 h-units. h double-buffer crosses WGs via
// relaxed agent-scope atomics (sc1: coherent at Infinity Cache, no L2
// flush/invalidate). Barrier: release add + relaxed spin + workgroup-acquire.
__global__ __launch_bounds__(384) void gru_mfma_kernel(
    const _Float16* __restrict__ xw,    // [2][512][32][1152]
    const _Float16* __restrict__ Whh,   // [2][1152][384] fp16 row-major
    const float* __restrict__ bhh_f, const float* __restrict__ bhh_b,
    _Float16* __restrict__ hglob,       // [2 dir][2 parity][32][384]
    _Float16* __restrict__ out16,       // [32][512][768]
    int* __restrict__ bar) {            // [2] arrive counters (zeroed)
  const int wg = blockIdx.x;
  const int dir = wg & 1, slice = wg >> 1;   // slice in [0,24)
  const int j0 = slice * 16;
  const int tid = threadIdx.x;
  const int lane = tid & 63, w = tid >> 6;   // 6 waves
  const int mt = w & 1, g = w >> 1;          // M-tile, gate
  const int c = lane & 15, q = lane >> 4;

  __shared__ float ghS[3][16][36];   // [gate][jj][b] fp32
  __shared__ float hfS[16][33];      // fp32 carry h for this WG's slice

  // ---- B-fragment preload (weights stay in VGPRs for all 512 steps) ----
  half8_t bfr[12];
  {
    const _Float16* wp = Whh + ((size_t)dir * H3_ + g * H_ + j0 + c) * H_ + q * 8;
#pragma unroll
    for (int kt = 0; kt < 12; ++kt) bfr[kt] = *(const half8_t*)(wp + kt * 32);
  }
  const float* bhh = dir ? bhh_b : bhh_f;
  // gate-phase mapping: threads [0,256): b = t>>3, jp = t&7 (two adjacent j)
  const int gb = tid >> 3, jp = tid & 7;
  float br0 = 0.f, br1 = 0.f, bz0 = 0.f, bz1 = 0.f, bn0 = 0.f, bn1 = 0.f;
  if (tid < 256) {
    br0 = bhh[j0 + jp * 2];       br1 = bhh[j0 + jp * 2 + 1];
    bz0 = bhh[H_ + j0 + jp * 2];  bz1 = bhh[H_ + j0 + jp * 2 + 1];
    bn0 = bhh[2 * H_ + j0 + jp * 2]; bn1 = bhh[2 * H_ + j0 + jp * 2 + 1];
  }

  for (int i = tid; i < 16 * 33; i += 384) ((float*)hfS)[i] = 0.f;
  __syncthreads();

  const int nwg_dir = 24;
  for (int step = 0; step < S_; ++step) {
    const int t = dir ? (S_ - 1 - step) : step;
    const int par = step & 1;

    // xw gate inputs (plain loads — L2 stays warm, no invalidates anywhere)
    float xr0 = 0.f, xr1 = 0.f, xz0 = 0.f, xz1 = 0.f, xn0 = 0.f, xn1 = 0.f;
    if (tid < 256) {
      const _Float16* xp =
          xw + (((size_t)dir * S_ + t) * B_ + gb) * H3_ + j0 + jp * 2;
      half2_t xr2 = *(const half2_t*)(xp);
      half2_t xz2 = *(const half2_t*)(xp + H_);
      half2_t xn2 = *(const half2_t*)(xp + 2 * H_);
      xr0 = (float)xr2.x; xr1 = (float)xr2.y;
      xz0 = (float)xz2.x; xz1 = (float)xz2.y;
      xn0 = (float)xn2.x; xn1 = (float)xn2.y;
    }

    // A-frags from h via relaxed agent atomics (sc1 -> Infinity Cache, coherent)
    unsigned long long* hp64 =
        (unsigned long long*)(hglob +
            (((size_t)dir * 2 + par) * B_ + (mt * 16 + c)) * H_);
    floatx4 acc = {};
#pragma unroll
    for (int kt = 0; kt < 12; ++kt) {
      unsigned long long v0 =
          __hip_atomic_load(hp64 + kt * 8 + q * 2, __ATOMIC_RELAXED, __HIP_MEMORY_SCOPE_AGENT);
      unsigned long long v1 =
          __hip_atomic_load(hp64 + kt * 8 + q * 2 + 1, __ATOMIC_RELAXED, __HIP_MEMORY_SCOPE_AGENT);
      union { unsigned long long u[2]; half8_t h; } cv;
      cv.u[0] = v0; cv.u[1] = v1;
      acc = __builtin_amdgcn_mfma_f32_16x16x32_f16(cv.h, bfr[kt], acc, 0, 0, 0);
    }
    // C layout: col jj = lane&15 = c, rows b = mt*16 + q*4 + r
    *(floatx4*)&ghS[g][c][mt * 16 + q * 4] = acc;
    __syncthreads();

    // gate phase: thread (b=gb, jpair=jp) computes two adjacent h values
    if (tid < 256) {
      const int jA = jp * 2, jB = jp * 2 + 1;
      float ar0 = ghS[0][jA][gb], az0 = ghS[1][jA][gb], an0 = ghS[2][jA][gb];
      float ar1 = ghS[0][jB][gb], az1 = ghS[1][jB][gb], an1 = ghS[2][jB][gb];
      float r0 = 1.f / (1.f + __expf(-(xr0 + ar0 + br0)));
      float r1 = 1.f / (1.f + __expf(-(xr1 + ar1 + br1)));
      float z0 = 1.f / (1.f + __expf(-(xz0 + az0 + bz0)));
      float z1 = 1.f / (1.f + __expf(-(xz1 + az1 + bz1)));
      float u0 = xn0 + r0 * (an0 + bn0);
      float u1 = xn1 + r1 * (an1 + bn1);
      float e0 = __expf(-2.f * u0), e1 = __expf(-2.f * u1);
      float nv0 = (1.f - e0) / (1.f + e0);
      float nv1 = (1.f - e1) / (1.f + e1);
      float h0 = (1.f - z0) * nv0 + z0 * hfS[jA][gb];
      float h1 = (1.f - z1) * nv1 + z1 * hfS[jB][gb];
      hfS[jA][gb] = h0;
      hfS[jB][gb] = h1;
      half2_t hh; hh.x = (_Float16)h0; hh.y = (_Float16)h1;
      unsigned hu = __builtin_bit_cast(unsigned, hh);
      // h_{t+1} slice -> other parity buffer, sc1 write-through (visible at MALL)
      unsigned* hnx = (unsigned*)(hglob +
          (((size_t)dir * 2 + (par ^ 1)) * B_ + gb) * H_ + j0 + jp * 2);
      __hip_atomic_store(hnx, hu, __ATOMIC_RELAXED, __HIP_MEMORY_SCOPE_AGENT);
      // out16 plain store (consumed after kernel boundary)
      *(unsigned*)&out16[((size_t)gb * S_ + t) * TWOH_ + dir * H_ + j0 + jp * 2] = hu;
    }
    __syncthreads();   // drains each thread's vmcnt before arrive (s_barrier semantics)

    if (tid == 0) {
      __hip_atomic_fetch_add(&bar[dir], 1, __ATOMIC_RELEASE, __HIP_MEMORY_SCOPE_AGENT);
      const int target = nwg_dir * (step + 1);
      while (__hip_atomic_load(&bar[dir], __ATOMIC_RELAXED, __HIP_MEMORY_SCOPE_AGENT) < target) {}
      (void)__hip_atomic_load(&bar[dir], __ATOMIC_ACQUIRE, __HIP_MEMORY_SCOPE_WORKGROUP);
    }
    __syncthreads();
  }
}

// ---------------- attention scores: tanh(out@Wattn^T + b) @ ctx ----------------
__global__ __launch_bounds__(256) void attn_score_kernel(
    const _Float16* __restrict__ A /*out16 [16384][768]*/,
    const _Float16* __restrict__ Bm /*Wattn16 [768][768]*/,
    const float* __restrict__ b_attn, const float* __restrict__ ctx,
    float* __restrict__ scores) {
  __shared__ _Float16 As[64][40];
  __shared__ _Float16 Bs[64][40];
  const int m0 = blockIdx.x * 64, n0 = blockIdx.y * 64;
  const int tid = threadIdx.x, lane = tid & 63, w = tid >> 6;
  const int wm = w >> 1, wn = w & 1;
  const int q = lane >> 4, c = lane & 15;
  floatx4 acc[2][2] = {};

  const int t = tid & 127;
  const int srow = t >> 1, skh = (t & 1) * 16;
  const _Float16* gsrc =
      (tid < 128 ? A + (size_t)(m0 + srow) * D_ : Bm + (size_t)(n0 + srow) * D_) + skh;
  _Float16* ldst = (tid < 128) ? &As[srow][skh] : &Bs[srow][skh];

  for (int k0 = 0; k0 < D_; k0 += 32) {
    half8_t v0 = *(const half8_t*)(gsrc + k0);
    half8_t v1 = *(const half8_t*)(gsrc + k0 + 8);
    __syncthreads();
    *(half8_t*)ldst = v0;
    *(half8_t*)(ldst + 8) = v1;
    __syncthreads();
    half8_t a0 = *(const half8_t*)&As[wm * 32 + c][q * 8];
    half8_t a1 = *(const half8_t*)&As[wm * 32 + 16 + c][q * 8];
    half8_t b0 = *(const half8_t*)&Bs[wn * 32 + c][q * 8];
    half8_t b1 = *(const half8_t*)&Bs[wn * 32 + 16 + c][q * 8];
    acc[0][0] = __builtin_amdgcn_mfma_f32_16x16x32_f16(a0, b0, acc[0][0], 0, 0, 0);
    acc[0][1] = __builtin_amdgcn_mfma_f32_16x16x32_f16(a0, b1, acc[0][1], 0, 0, 0);
    acc[1][0] = __builtin_amdgcn_mfma_f32_16x16x32_f16(a1, b0, acc[1][0], 0, 0, 0);
    acc[1][1] = __builtin_amdgcn_mfma_f32_16x16x32_f16(a1, b1, acc[1][1], 0, 0, 0);
  }
  for (int mi = 0; mi < 2; ++mi)
    for (int ni = 0; ni < 2; ++ni)
      for (int r = 0; r < 4; ++r) {
        int n = n0 + wn * 32 + ni * 16 + c;
        float vv = tanhf(acc[mi][ni][r] + b_attn[n]) * ctx[n];
        vv += __shfl_xor(vv, 1);
        vv += __shfl_xor(vv, 2);
        vv += __shfl_xor(vv, 4);
        vv += __shfl_xor(vv, 8);
        if (c == 0) {
          int m = m0 + wm * 32 + mi * 16 + q * 4 + r;
          atomicAdd(&scores[m], vv);
        }
      }
}

// ---------------- softmax over S per batch ----------------
__global__ __launch_bounds__(256) void softmax_kernel(const float* __restrict__ scores,
                                                      float* __restrict__ attn) {
  const int b = blockIdx.x, tid = threadIdx.x;
  __shared__ float red[8];
  float s0 = scores[b * S_ + tid], s1 = scores[b * S_ + 256 + tid];
  float m = fmaxf(s0, s1);
  for (int off = 1; off < 64; off <<= 1) m = fmaxf(m, __shfl_xor(m, off));
  int wv = tid >> 6;
  if ((tid & 63) == 0) red[wv] = m;
  __syncthreads();
  m = fmaxf(fmaxf(red[0], red[1]), fmaxf(red[2], red[3]));
  float e0 = expf(s0 - m), e1 = expf(s1 - m);
  float sum = e0 + e1;
  for (int off = 1; off < 64; off <<= 1) sum += __shfl_xor(sum, off);
  if ((tid & 63) == 0) red[4 + wv] = sum;
  __syncthreads();
  sum = red[4] + red[5] + red[6] + red[7];
  float inv = 1.0f / sum;
  attn[b * S_ + tid] = e0 * inv;
  attn[b * S_ + 256 + tid] = e1 * inv;
}

// ---------------- doc embedding: attn-weighted sum ----------------
__global__ __launch_bounds__(384) void doc_kernel(const float* __restrict__ attn,
                                                  const _Float16* __restrict__ out16,
                                                  float* __restrict__ dout) {
  const int b = blockIdx.x, tid = threadIdx.x;
  __shared__ float at[S_];
  for (int i = tid; i < S_; i += 384) at[i] = attn[b * S_ + i];
  __syncthreads();
  const half2_t* p = (const half2_t*)(out16 + (size_t)b * S_ * TWOH_) + tid;
  float acc0 = 0.f, acc1 = 0.f;
  for (int s = 0; s < S_; ++s) {
    half2_t h = p[(size_t)s * (TWOH_ / 2)];
    float wgt = at[s];
    acc0 += wgt * (float)h.x;
    acc1 += wgt * (float)h.y;
  }
  dout[b * TWOH_ + tid * 2] = acc0;
  dout[b * TWOH_ + tid * 2 + 1] = acc1;
}

// ---------------- host ----------------
extern "C" void kernel_launch(void* const* d_in, const int* in_sizes, int n_in,
                              void* d_out, int out_size, void* d_ws, size_t ws_size,
                              hipStream_t stream) {
  const float* ip     = (const float*)d_in[0];
  const float* W_ih_f = (const float*)d_in[1];
  const float* W_hh_f = (const float*)d_in[2];
  const float* b_ih_f = (const float*)d_in[3];
  const float* b_hh_f_p = (const float*)d_in[4];
  const float* W_ih_b = (const float*)d_in[5];
  const float* W_hh_b = (const float*)d_in[6];
  const float* b_ih_b = (const float*)d_in[7];
  const float* b_hh_b_p = (const float*)d_in[8];
  const float* W_attn = (const float*)d_in[9];
  const float* b_attn = (const float*)d_in[10];
  const float* context = (const float*)d_in[11];
  float* doc = (float*)d_out;

  char* ws = (char*)d_ws;
  size_t off = 0;
  auto alloc = [&](size_t bytes) {
    char* p = ws + off;
    off += (bytes + 255) & ~(size_t)255;
    return p;
  };
  _Float16* ip16    = (_Float16*)alloc((size_t)M_ * D_ * 2);          // 25.2 MB
  _Float16* Wih16   = (_Float16*)alloc((size_t)N2_ * D_ * 2);         // 3.5 MB
  _Float16* Whh16   = (_Float16*)alloc((size_t)2 * H3_ * H_ * 2);     // 1.8 MB
  _Float16* Wattn16 = (_Float16*)alloc((size_t)TWOH_ * TWOH_ * 2);    // 1.2 MB
  _Float16* xw      = (_Float16*)alloc((size_t)2 * S_ * B_ * H3_ * 2);// 75.5 MB
  _Float16* out16   = (_Float16*)alloc((size_t)B_ * S_ * TWOH_ * 2);  // 25.2 MB
  _Float16* hglob   = (_Float16*)alloc((size_t)2 * 2 * B_ * H_ * 2);  // 98 KB
  int*      bar     = (int*)alloc(256);
  float* scores     = (float*)alloc((size_t)M_ * 4);
  float* attn       = (float*)alloc((size_t)M_ * 4);

  // 1. converts
  cvt_f32_f16_kernel<<<(M_ * D_ / 4 + 255) / 256, 256, 0, stream>>>(ip, ip16, M_ * D_ / 4);
  cvt_f32_f16_kernel<<<(H3_ * D_ / 4 + 255) / 256, 256, 0, stream>>>(W_ih_f, Wih16, H3_ * D_ / 4);
  cvt_f32_f16_kernel<<<(H3_ * D_ / 4 + 255) / 256, 256, 0, stream>>>(W_ih_b, Wih16 + (size_t)H3_ * D_, H3_ * D_ / 4);
  cvt_f32_f16_kernel<<<(H3_ * H_ / 4 + 255) / 256, 256, 0, stream>>>(W_hh_f, Whh16, H3_ * H_ / 4);
  cvt_f32_f16_kernel<<<(H3_ * H_ / 4 + 255) / 256, 256, 0, stream>>>(W_hh_b, Whh16 + (size_t)H3_ * H_, H3_ * H_ / 4);
  cvt_f32_f16_kernel<<<(TWOH_ * TWOH_ / 4 + 255) / 256, 256, 0, stream>>>(W_attn, Wattn16, TWOH_ * TWOH_ / 4);

  // 2. input projection GEMM
  gemm_xw_kernel<<<dim3(M_ / 64, N2_ / 64), 256, 0, stream>>>(ip16, Wih16, b_ih_f, b_ih_b, xw);

  // 3. recurrence: zero h double-buffer + barrier counters, cooperative launch
  hipMemsetAsync(hglob, 0, (size_t)2 * 2 * B_ * H_ * 2, stream);
  hipMemsetAsync(bar, 0, 256, stream);
  {
    const _Float16* xw_a = xw;
    const _Float16* whh_a = Whh16;
    const float* bf_a = b_hh_f_p;
    const float* bb_a = b_hh_b_p;
    _Float16* hg_a = hglob;
    _Float16* o16_a = out16;
    int* bar_a = bar;
    void* args[] = {(void*)&xw_a, (void*)&whh_a, (void*)&bf_a, (void*)&bb_a,
                    (void*)&hg_a, (void*)&o16_a, (void*)&bar_a};
    hipLaunchCooperativeKernel((const void*)gru_mfma_kernel, dim3(48), dim3(384),
                               args, 0, stream);
  }

  // 4. attention scores
  hipMemsetAsync(scores, 0, (size_t)M_ * 4, stream);
  attn_score_kernel<<<dim3(M_ / 64, TWOH_ / 64), 256, 0, stream>>>(out16, Wattn16, b_attn, context, scores);

  // 5. softmax + weighted sum
  softmax_kernel<<<B_, 256, 0, stream>>>(scores, attn);
  doc_kernel<<<B_, 384, 0, stream>>>(attn, out16, doc);
}

// Round 4
// 2216.427 us; speedup vs baseline: 1.9312x; 1.9312x over previous
//
#include <hip/hip_runtime.h>
#include <hip/hip_fp16.h>

typedef _Float16 half2_t __attribute__((ext_vector_type(2)));
typedef _Float16 half4_t __attribute__((ext_vector_type(4)));
typedef _Float16 half8_t __attribute__((ext_vector_type(8)));
typedef float floatx4 __attribute__((ext_vector_type(4)));

#define B_   32
#define S_   512
#define D_   768
#define H_   384
#define H3_  1152      // 3*H
#define M_   (B_*S_)   // 16384
#define N2_  (2*H3_)   // 2304
#define TWOH_ 768
#define NWG_DIR 6
#define JSPAN 64       // j-slice per WG

// ---- coherent (cache-bypassing, coalescing) 16B load / 8B store helpers ----
__device__ __forceinline__ int4 load16_cc(const void* p) {
  int4 r;
  unsigned long long a = (unsigned long long)p;
  asm volatile("global_load_dwordx4 %0, %1, off sc0 sc1\n\t"
               "s_waitcnt vmcnt(0)"
               : "=v"(r) : "v"(a) : "memory");
  return r;
}
__device__ __forceinline__ void load16_cc3(const void* p0, const void* p1, const void* p2,
                                           int4& v0, int4& v1, int4& v2) {
  unsigned long long a0 = (unsigned long long)p0;
  unsigned long long a1 = (unsigned long long)p1;
  unsigned long long a2 = (unsigned long long)p2;
  asm volatile("global_load_dwordx4 %0, %3, off sc0 sc1\n\t"
               "global_load_dwordx4 %1, %4, off sc0 sc1\n\t"
               "global_load_dwordx4 %2, %5, off sc0 sc1\n\t"
               "s_waitcnt vmcnt(0)"
               : "=&v"(v0), "=&v"(v1), "=&v"(v2)
               : "v"(a0), "v"(a1), "v"(a2) : "memory");
}
__device__ __forceinline__ void store8_cc(void* p, int2 v) {
  unsigned long long a = (unsigned long long)p;
  asm volatile("global_store_dwordx2 %0, %1, off sc0 sc1"
               :: "v"(a), "v"(v) : "memory");
}
__device__ __forceinline__ void wait_vm0() {
  asm volatile("s_waitcnt vmcnt(0)" ::: "memory");
}

// ---------------- generic fp32 -> fp16 convert (vec4) ----------------
__global__ void cvt_f32_f16_kernel(const float* __restrict__ src,
                                   _Float16* __restrict__ dst, int n4) {
  int i = blockIdx.x * blockDim.x + threadIdx.x;
  if (i >= n4) return;
  float4 v = ((const float4*)src)[i];
  half4_t h = {(_Float16)v.x, (_Float16)v.y, (_Float16)v.z, (_Float16)v.w};
  ((half4_t*)dst)[i] = h;
}

// ---------------- input-projection GEMM (fp16 MFMA) ----------------
__global__ __launch_bounds__(256) void gemm_xw_kernel(
    const _Float16* __restrict__ A, const _Float16* __restrict__ Bm,
    const float* __restrict__ bias_f, const float* __restrict__ bias_b,
    _Float16* __restrict__ xw) {
  __shared__ _Float16 As[64][40];
  __shared__ _Float16 Bs[64][40];
  const int m0 = blockIdx.x * 64, n0 = blockIdx.y * 64;
  const int tid = threadIdx.x, lane = tid & 63, w = tid >> 6;
  const int wm = w >> 1, wn = w & 1;
  const int q = lane >> 4, c = lane & 15;
  floatx4 acc[2][2] = {};

  const int t = tid & 127;
  const int srow = t >> 1, skh = (t & 1) * 16;
  const _Float16* gsrc =
      (tid < 128 ? A + (size_t)(m0 + srow) * D_ : Bm + (size_t)(n0 + srow) * D_) + skh;
  _Float16* ldst = (tid < 128) ? &As[srow][skh] : &Bs[srow][skh];

  for (int k0 = 0; k0 < D_; k0 += 32) {
    half8_t v0 = *(const half8_t*)(gsrc + k0);
    half8_t v1 = *(const half8_t*)(gsrc + k0 + 8);
    __syncthreads();
    *(half8_t*)ldst = v0;
    *(half8_t*)(ldst + 8) = v1;
    __syncthreads();
    half8_t a0 = *(const half8_t*)&As[wm * 32 + c][q * 8];
    half8_t a1 = *(const half8_t*)&As[wm * 32 + 16 + c][q * 8];
    half8_t b0 = *(const half8_t*)&Bs[wn * 32 + c][q * 8];
    half8_t b1 = *(const half8_t*)&Bs[wn * 32 + 16 + c][q * 8];
    acc[0][0] = __builtin_amdgcn_mfma_f32_16x16x32_f16(a0, b0, acc[0][0], 0, 0, 0);
    acc[0][1] = __builtin_amdgcn_mfma_f32_16x16x32_f16(a0, b1, acc[0][1], 0, 0, 0);
    acc[1][0] = __builtin_amdgcn_mfma_f32_16x16x32_f16(a1, b0, acc[1][0], 0, 0, 0);
    acc[1][1] = __builtin_amdgcn_mfma_f32_16x16x32_f16(a1, b1, acc[1][1], 0, 0, 0);
  }
  for (int mi = 0; mi < 2; ++mi)
    for (int ni = 0; ni < 2; ++ni)
      for (int r = 0; r < 4; ++r) {
        int m = m0 + wm * 32 + mi * 16 + q * 4 + r;
        int n = n0 + wn * 32 + ni * 16 + c;
        int dir = n >= H3_;
        int nn = n - dir * H3_;
        float bv = dir ? bias_b[nn] : bias_f[nn];
        float vv = acc[mi][ni][r] + bv;
        int s = m & (S_ - 1), bb = m >> 9;
        xw[(((size_t)dir * S_ + s) * B_ + bb) * H3_ + nn] = (_Float16)vv;
      }
}

// ---------------- GRU recurrence v3: 12 WGs, LDS-staged h, flag barrier ----
// 12 WGs = 2 dirs x 6 slices of 64 j. 512 threads = 8 waves = 2 btiles x 4 jtiles,
// each wave holds 3 gates' 16x384 weight tiles (144 VGPRs). Per step: coalesced
// sc0sc1 h gather -> LDS, 36 MFMAs/wave, fp32 gates (carry in regs), coalesced
// sc0sc1 h scatter, per-WG monotonic flag barrier (no RMW).
__global__ __launch_bounds__(512, 2) void gru_mfma_kernel(
    const _Float16* __restrict__ xw,    // [2][512][32][1152]
    const _Float16* __restrict__ Whh,   // [2][1152][384] fp16 row-major
    const float* __restrict__ bhh_f, const float* __restrict__ bhh_b,
    _Float16* __restrict__ hglob,       // [2 dir][2 parity][32][384]
    _Float16* __restrict__ out16,       // [32][512][768]
    int* __restrict__ bar) {            // per-WG step flags (zeroed)
  const int wg = blockIdx.x;
  const int dir = wg / NWG_DIR;
  const int wgj = wg % NWG_DIR;
  const int j0w = wgj * JSPAN;
  const int tid = threadIdx.x, lane = tid & 63, w = tid >> 6;
  const int bt = w & 1, jt = w >> 1;     // btile 0..1, jtile 0..3
  const int c = lane & 15, q = lane >> 4;

  __shared__ __align__(16) _Float16 hS[32 * 392];   // h staged, pad 392 (2-way free)
  __shared__ __align__(16) float ghS[3 * 32 * 68];  // [gate][b][j] pad 68

  // ---- weight B-fragments: [gate][kt], resident all 512 steps ----
  half8_t bfr[3][12];
  {
    const int jglob = j0w + jt * 16 + c;
#pragma unroll
    for (int g = 0; g < 3; ++g) {
      const _Float16* wp = Whh + ((size_t)dir * H3_ + g * H_ + jglob) * H_ + q * 8;
#pragma unroll
      for (int kt = 0; kt < 12; ++kt) bfr[g][kt] = *(const half8_t*)(wp + kt * 32);
    }
  }
  const float* bhh = dir ? bhh_b : bhh_f;
  const int gb = tid >> 4, jq = tid & 15;  // gate-phase: b, j-quad
  const int jg4 = j0w + jq * 4;
  float br[4], bz[4], bn[4], hc[4];
#pragma unroll
  for (int i = 0; i < 4; ++i) {
    br[i] = bhh[jg4 + i];
    bz[i] = bhh[H_ + jg4 + i];
    bn[i] = bhh[2 * H_ + jg4 + i];
    hc[i] = 0.f;
  }
  int* flg = bar + dir * 256;   // 6 flags, 64B apart

  for (int step = 0; step < S_; ++step) {
    const int t = dir ? (S_ - 1 - step) : step;
    const int par = step & 1;

    // xw prefetch (plain cached loads; in flight during the poll)
    const _Float16* xp = xw + (((size_t)dir * S_ + t) * B_ + gb) * H3_ + jg4;
    half4_t xr4 = *(const half4_t*)(xp);
    half4_t xz4 = *(const half4_t*)(xp + H_);
    half4_t xn4 = *(const half4_t*)(xp + 2 * H_);

    // wait until all 6 producer WGs of this dir finished step-1
    if (step > 0 && w == 0) {
      int v;
      do {
        v = (lane < NWG_DIR)
                ? __hip_atomic_load(&flg[lane * 16], __ATOMIC_RELAXED,
                                    __HIP_MEMORY_SCOPE_AGENT)
                : 0x7fffffff;
      } while (!__all(v >= step));
    }
    __syncthreads();

    // stage full h (32x384 fp16 = 24 KB) into LDS: 1536 coherent 16B chunks
    {
      const _Float16* hb = hglob + ((size_t)dir * 2 + par) * B_ * H_;
      int g0 = tid, g1 = tid + 512, g2 = tid + 1024;
      int4 v0, v1, v2;
      load16_cc3(hb + (g0 / 48) * H_ + (g0 % 48) * 8,
                 hb + (g1 / 48) * H_ + (g1 % 48) * 8,
                 hb + (g2 / 48) * H_ + (g2 % 48) * 8, v0, v1, v2);
      *(int4*)&hS[(g0 / 48) * 392 + (g0 % 48) * 8] = v0;
      *(int4*)&hS[(g1 / 48) * 392 + (g1 % 48) * 8] = v1;
      *(int4*)&hS[(g2 / 48) * 392 + (g2 % 48) * 8] = v2;
    }
    __syncthreads();

    // MFMA: 3 gate-chains per wave, A-frags from LDS
    floatx4 a0 = {}, a1 = {}, a2 = {};
    {
      const _Float16* hrow = &hS[(bt * 16 + c) * 392 + q * 8];
#pragma unroll
      for (int kt = 0; kt < 12; ++kt) {
        half8_t af = *(const half8_t*)(hrow + kt * 32);
        a0 = __builtin_amdgcn_mfma_f32_16x16x32_f16(af, bfr[0][kt], a0, 0, 0, 0);
        a1 = __builtin_amdgcn_mfma_f32_16x16x32_f16(af, bfr[1][kt], a1, 0, 0, 0);
        a2 = __builtin_amdgcn_mfma_f32_16x16x32_f16(af, bfr[2][kt], a2, 0, 0, 0);
      }
    }
#pragma unroll
    for (int r = 0; r < 4; ++r) {
      int brow = bt * 16 + q * 4 + r;
      ghS[(0 * 32 + brow) * 68 + jt * 16 + c] = a0[r];
      ghS[(1 * 32 + brow) * 68 + jt * 16 + c] = a1[r];
      ghS[(2 * 32 + brow) * 68 + jt * 16 + c] = a2[r];
    }
    __syncthreads();

    // gate phase: thread (b=gb, j-quad=jq), carry hc in registers
    floatx4 arv = *(floatx4*)&ghS[(0 * 32 + gb) * 68 + jq * 4];
    floatx4 azv = *(floatx4*)&ghS[(1 * 32 + gb) * 68 + jq * 4];
    floatx4 anv = *(floatx4*)&ghS[(2 * 32 + gb) * 68 + jq * 4];
    half4_t hh;
#pragma unroll
    for (int i = 0; i < 4; ++i) {
      float rr = 1.f / (1.f + __expf(-((float)xr4[i] + arv[i] + br[i])));
      float zz = 1.f / (1.f + __expf(-((float)xz4[i] + azv[i] + bz[i])));
      float u = (float)xn4[i] + rr * (anv[i] + bn[i]);
      float e = __expf(-2.f * u);
      float nv = (1.f - e) / (1.f + e);
      hc[i] = (1.f - zz) * nv + zz * hc[i];
      hh[i] = (_Float16)hc[i];
    }
    // h_{t+1} -> other parity buffer (coherent write-through)
    store8_cc(hglob + (((size_t)dir * 2 + (par ^ 1)) * B_ + gb) * H_ + jg4,
              __builtin_bit_cast(int2, hh));
    wait_vm0();          // each thread drains its own stores
    __syncthreads();     // all WG stores drained
    if (tid == 0)
      __hip_atomic_store(&flg[wgj * 16], step + 1, __ATOMIC_RELAXED,
                         __HIP_MEMORY_SCOPE_AGENT);
    // out16 off the critical path (consumed after kernel boundary)
    *(half4_t*)&out16[((size_t)gb * S_ + t) * TWOH_ + dir * H_ + jg4] = hh;
  }
}

// ---------------- attention scores: tanh(out@Wattn^T + b) @ ctx ----------------
__global__ __launch_bounds__(256) void attn_score_kernel(
    const _Float16* __restrict__ A /*out16 [16384][768]*/,
    const _Float16* __restrict__ Bm /*Wattn16 [768][768]*/,
    const float* __restrict__ b_attn, const float* __restrict__ ctx,
    float* __restrict__ scores) {
  __shared__ _Float16 As[64][40];
  __shared__ _Float16 Bs[64][40];
  const int m0 = blockIdx.x * 64, n0 = blockIdx.y * 64;
  const int tid = threadIdx.x, lane = tid & 63, w = tid >> 6;
  const int wm = w >> 1, wn = w & 1;
  const int q = lane >> 4, c = lane & 15;
  floatx4 acc[2][2] = {};

  const int t = tid & 127;
  const int srow = t >> 1, skh = (t & 1) * 16;
  const _Float16* gsrc =
      (tid < 128 ? A + (size_t)(m0 + srow) * D_ : Bm + (size_t)(n0 + srow) * D_) + skh;
  _Float16* ldst = (tid < 128) ? &As[srow][skh] : &Bs[srow][skh];

  for (int k0 = 0; k0 < D_; k0 += 32) {
    half8_t v0 = *(const half8_t*)(gsrc + k0);
    half8_t v1 = *(const half8_t*)(gsrc + k0 + 8);
    __syncthreads();
    *(half8_t*)ldst = v0;
    *(half8_t*)(ldst + 8) = v1;
    __syncthreads();
    half8_t a0 = *(const half8_t*)&As[wm * 32 + c][q * 8];
    half8_t a1 = *(const half8_t*)&As[wm * 32 + 16 + c][q * 8];
    half8_t b0 = *(const half8_t*)&Bs[wn * 32 + c][q * 8];
    half8_t b1 = *(const half8_t*)&Bs[wn * 32 + 16 + c][q * 8];
    acc[0][0] = __builtin_amdgcn_mfma_f32_16x16x32_f16(a0, b0, acc[0][0], 0, 0, 0);
    acc[0][1] = __builtin_amdgcn_mfma_f32_16x16x32_f16(a0, b1, acc[0][1], 0, 0, 0);
    acc[1][0] = __builtin_amdgcn_mfma_f32_16x16x32_f16(a1, b0, acc[1][0], 0, 0, 0);
    acc[1][1] = __builtin_amdgcn_mfma_f32_16x16x32_f16(a1, b1, acc[1][1], 0, 0, 0);
  }
  for (int mi = 0; mi < 2; ++mi)
    for (int ni = 0; ni < 2; ++ni)
      for (int r = 0; r < 4; ++r) {
        int n = n0 + wn * 32 + ni * 16 + c;
        float vv = tanhf(acc[mi][ni][r] + b_attn[n]) * ctx[n];
        vv += __shfl_xor(vv, 1);
        vv += __shfl_xor(vv, 2);
        vv += __shfl_xor(vv, 4);
        vv += __shfl_xor(vv, 8);
        if (c == 0) {
          int m = m0 + wm * 32 + mi * 16 + q * 4 + r;
          atomicAdd(&scores[m], vv);
        }
      }
}

// ---------------- softmax over S per batch ----------------
__global__ __launch_bounds__(256) void softmax_kernel(const float* __restrict__ scores,
                                                      float* __restrict__ attn) {
  const int b = blockIdx.x, tid = threadIdx.x;
  __shared__ float red[8];
  float s0 = scores[b * S_ + tid], s1 = scores[b * S_ + 256 + tid];
  float m = fmaxf(s0, s1);
  for (int off = 1; off < 64; off <<= 1) m = fmaxf(m, __shfl_xor(m, off));
  int wv = tid >> 6;
  if ((tid & 63) == 0) red[wv] = m;
  __syncthreads();
  m = fmaxf(fmaxf(red[0], red[1]), fmaxf(red[2], red[3]));
  float e0 = expf(s0 - m), e1 = expf(s1 - m);
  float sum = e0 + e1;
  for (int off = 1; off < 64; off <<= 1) sum += __shfl_xor(sum, off);
  if ((tid & 63) == 0) red[4 + wv] = sum;
  __syncthreads();
  sum = red[4] + red[5] + red[6] + red[7];
  float inv = 1.0f / sum;
  attn[b * S_ + tid] = e0 * inv;
  attn[b * S_ + 256 + tid] = e1 * inv;
}

// ---------------- doc embedding: attn-weighted sum ----------------
__global__ __launch_bounds__(384) void doc_kernel(const float* __restrict__ attn,
                                                  const _Float16* __restrict__ out16,
                                                  float* __restrict__ dout) {
  const int b = blockIdx.x, tid = threadIdx.x;
  __shared__ float at[S_];
  for (int i = tid; i < S_; i += 384) at[i] = attn[b * S_ + i];
  __syncthreads();
  const half2_t* p = (const half2_t*)(out16 + (size_t)b * S_ * TWOH_) + tid;
  float acc0 = 0.f, acc1 = 0.f;
  for (int s = 0; s < S_; ++s) {
    half2_t h = p[(size_t)s * (TWOH_ / 2)];
    float wgt = at[s];
    acc0 += wgt * (float)h.x;
    acc1 += wgt * (float)h.y;
  }
  dout[b * TWOH_ + tid * 2] = acc0;
  dout[b * TWOH_ + tid * 2 + 1] = acc1;
}

// ---------------- host ----------------
extern "C" void kernel_launch(void* const* d_in, const int* in_sizes, int n_in,
                              void* d_out, int out_size, void* d_ws, size_t ws_size,
                              hipStream_t stream) {
  const float* ip     = (const float*)d_in[0];
  const float* W_ih_f = (const float*)d_in[1];
  const float* W_hh_f = (const float*)d_in[2];
  const float* b_ih_f = (const float*)d_in[3];
  const float* b_hh_f_p = (const float*)d_in[4];
  const float* W_ih_b = (const float*)d_in[5];
  const float* W_hh_b = (const float*)d_in[6];
  const float* b_ih_b = (const float*)d_in[7];
  const float* b_hh_b_p = (const float*)d_in[8];
  const float* W_attn = (const float*)d_in[9];
  const float* b_attn = (const float*)d_in[10];
  const float* context = (const float*)d_in[11];
  float* doc = (float*)d_out;

  char* ws = (char*)d_ws;
  size_t off = 0;
  auto alloc = [&](size_t bytes) {
    char* p = ws + off;
    off += (bytes + 255) & ~(size_t)255;
    return p;
  };
  _Float16* ip16    = (_Float16*)alloc((size_t)M_ * D_ * 2);          // 25.2 MB
  _Float16* Wih16   = (_Float16*)alloc((size_t)N2_ * D_ * 2);         // 3.5 MB
  _Float16* Whh16   = (_Float16*)alloc((size_t)2 * H3_ * H_ * 2);     // 1.8 MB
  _Float16* Wattn16 = (_Float16*)alloc((size_t)TWOH_ * TWOH_ * 2);    // 1.2 MB
  _Float16* xw      = (_Float16*)alloc((size_t)2 * S_ * B_ * H3_ * 2);// 75.5 MB
  _Float16* out16   = (_Float16*)alloc((size_t)B_ * S_ * TWOH_ * 2);  // 25.2 MB
  _Float16* hglob   = (_Float16*)alloc((size_t)2 * 2 * B_ * H_ * 2);  // 98 KB
  int*      bar     = (int*)alloc(4096);
  float* scores     = (float*)alloc((size_t)M_ * 4);
  float* attn       = (float*)alloc((size_t)M_ * 4);

  // 1. converts
  cvt_f32_f16_kernel<<<(M_ * D_ / 4 + 255) / 256, 256, 0, stream>>>(ip, ip16, M_ * D_ / 4);
  cvt_f32_f16_kernel<<<(H3_ * D_ / 4 + 255) / 256, 256, 0, stream>>>(W_ih_f, Wih16, H3_ * D_ / 4);
  cvt_f32_f16_kernel<<<(H3_ * D_ / 4 + 255) / 256, 256, 0, stream>>>(W_ih_b, Wih16 + (size_t)H3_ * D_, H3_ * D_ / 4);
  cvt_f32_f16_kernel<<<(H3_ * H_ / 4 + 255) / 256, 256, 0, stream>>>(W_hh_f, Whh16, H3_ * H_ / 4);
  cvt_f32_f16_kernel<<<(H3_ * H_ / 4 + 255) / 256, 256, 0, stream>>>(W_hh_b, Whh16 + (size_t)H3_ * H_, H3_ * H_ / 4);
  cvt_f32_f16_kernel<<<(TWOH_ * TWOH_ / 4 + 255) / 256, 256, 0, stream>>>(W_attn, Wattn16, TWOH_ * TWOH_ / 4);

  // 2. input projection GEMM
  gemm_xw_kernel<<<dim3(M_ / 64, N2_ / 64), 256, 0, stream>>>(ip16, Wih16, b_ih_f, b_ih_b, xw);

  // 3. recurrence: zero h double-buffer + flags, cooperative launch (12 WGs)
  hipMemsetAsync(hglob, 0, (size_t)2 * 2 * B_ * H_ * 2, stream);
  hipMemsetAsync(bar, 0, 4096, stream);
  {
    const _Float16* xw_a = xw;
    const _Float16* whh_a = Whh16;
    const float* bf_a = b_hh_f_p;
    const float* bb_a = b_hh_b_p;
    _Float16* hg_a = hglob;
    _Float16* o16_a = out16;
    int* bar_a = bar;
    void* args[] = {(void*)&xw_a, (void*)&whh_a, (void*)&bf_a, (void*)&bb_a,
                    (void*)&hg_a, (void*)&o16_a, (void*)&bar_a};
    hipLaunchCooperativeKernel((const void*)gru_mfma_kernel, dim3(2 * NWG_DIR),
                               dim3(512), args, 0, stream);
  }

  // 4. attention scores
  hipMemsetAsync(scores, 0, (size_t)M_ * 4, stream);
  attn_score_kernel<<<dim3(M_ / 64, TWOH_ / 64), 256, 0, stream>>>(out16, Wattn16, b_attn, context, scores);

  // 5. softmax + weighted sum
  softmax_kernel<<<B_, 256, 0, stream>>>(scores, attn);
  doc_kernel<<<B_, 384, 0, stream>>>(attn, out16, doc);
}